// Round 8
// baseline (735.849 us; speedup 1.0000x reference)
//
#include <hip/hip_runtime.h>
#include <math.h>

#define NEGF -1000000000.0f
#define EPSF 1e-7f

// B=32, T=256, IN=64, H=128, 4H=512, TOP_K=5

// Pin a float4's components in VGPRs (anti-sink). Only effective when the
// register GRANT is large enough; grant evidence across rounds:
//   1024-thr workgroups -> always 64 VGPRs (r2,r3,r6,r7)
//   512-thr + waves_per_eu(2,2) -> 128 (r4), 88 on demand (r5)
// This round: 512-thr + waves_per_eu(1,1); flat_work_group_size(512) caps
// at 256 VGPRs architecturally, which is what we need for 128 fp32 weights.
#define KEEP4(v) __asm__ volatile("" : "+v"((v).x), "+v"((v).y), "+v"((v).z), "+v"((v).w))

__device__ __forceinline__ float fsigmoid(float x) {
  return 1.0f / (1.0f + __expf(-x));               // overflow -> correct limit
}
__device__ __forceinline__ float ftanh(float x) {
  return 1.0f - 2.0f / (1.0f + __expf(2.0f * x));  // limits +-1: correct
}

// wave64 all-reduce sum via DPP (row_shr 1/2/4/8 + row_bcast 15/31), ~35 cyc.
__device__ __forceinline__ float wave_allsum(float v) {
#if __has_builtin(__builtin_amdgcn_update_dpp) && __has_builtin(__builtin_amdgcn_readlane)
  float f = v;
#define DPPSTEP(ctrl, rmask) { \
    int t = __builtin_amdgcn_update_dpp(0, __builtin_bit_cast(int, f), \
                                        ctrl, rmask, 0xf, true); \
    f += __builtin_bit_cast(float, t); }
  DPPSTEP(0x111, 0xf)   // row_shr:1
  DPPSTEP(0x112, 0xf)   // row_shr:2
  DPPSTEP(0x114, 0xf)   // row_shr:4
  DPPSTEP(0x118, 0xf)   // row_shr:8  -> lane15 of each row has row sum
  DPPSTEP(0x142, 0xa)   // row_bcast:15 into rows 1,3
  DPPSTEP(0x143, 0x8)   // row_bcast:31 into row 3 -> lane 63 = total
#undef DPPSTEP
  return __builtin_bit_cast(float,
      __builtin_amdgcn_readlane(__builtin_bit_cast(int, f), 63));
#else
  for (int off = 1; off < 64; off <<= 1) v += __shfl_xor(v, off, 64);
  return v;
#endif
}

// Kernel 1: xw[b][t][g] = x[b][t] . W_ih[g] + (b_ih[g]+b_hh[g])
// grid (8, 32) = (T/32, B), 256 blocks = 1/CU. Thread g owns gate g,
// 16 pinned float4 of W_ih; 32 timesteps per block, ONE barrier total.
__global__
__attribute__((amdgpu_flat_work_group_size(512, 512), amdgpu_waves_per_eu(2, 2)))
void xw_kernel(
    const float* __restrict__ x, const float* __restrict__ W_ih,
    const float* __restrict__ b_ih, const float* __restrict__ b_hh,
    float* __restrict__ xw)
{
  const int t0 = blockIdx.x * 32;
  const int b  = blockIdx.y;
  const int g  = threadIdx.x;

  __shared__ float sx[32][64];               // 8 KB
  {
    // 2048 floats = 512 float4: thread tid loads float4 #tid
    int row = threadIdx.x >> 4, col = (threadIdx.x & 15) << 2;
    *(float4*)&sx[row][col] =
        *(const float4*)&x[(size_t)(b * 256 + t0 + row) * 64 + col];
  }
  const float4* wr = (const float4*)(W_ih + (size_t)g * 64);
  float4 w0 = wr[0], w1 = wr[1], w2 = wr[2],  w3 = wr[3],
         w4 = wr[4], w5 = wr[5], w6 = wr[6],  w7 = wr[7],
         w8 = wr[8], w9 = wr[9], w10 = wr[10], w11 = wr[11],
         w12 = wr[12], w13 = wr[13], w14 = wr[14], w15 = wr[15];
  KEEP4(w0); KEEP4(w1); KEEP4(w2); KEEP4(w3);
  KEEP4(w4); KEEP4(w5); KEEP4(w6); KEEP4(w7);
  KEEP4(w8); KEEP4(w9); KEEP4(w10); KEEP4(w11);
  KEEP4(w12); KEEP4(w13); KEEP4(w14); KEEP4(w15);
  const float bias = b_ih[g] + b_hh[g];
  __syncthreads();
  for (int tt = 0; tt < 32; ++tt) {
    const float4* sx4 = (const float4*)(&sx[tt][0]);
    float a0 = bias, a1 = 0.0f, a2 = 0.0f, a3 = 0.0f;
#define XSTEP(q) { float4 hv = sx4[q]; \
    a0 = fmaf(w##q.x, hv.x, a0); a1 = fmaf(w##q.y, hv.y, a1); \
    a2 = fmaf(w##q.z, hv.z, a2); a3 = fmaf(w##q.w, hv.w, a3); }
    XSTEP(0) XSTEP(1) XSTEP(2) XSTEP(3) XSTEP(4) XSTEP(5) XSTEP(6) XSTEP(7)
    XSTEP(8) XSTEP(9) XSTEP(10) XSTEP(11) XSTEP(12) XSTEP(13) XSTEP(14) XSTEP(15)
#undef XSTEP
    xw[(size_t)(b * 256 + t0 + tt) * 512 + g] = (a0 + a1) + (a2 + a3);
  }
}

// Kernel 2: full recurrence, one block per batch element, 512 threads.
// Thread g owns gate g: 128 fp32 W_hh weights in 32 pinned float4s.
// waves_per_eu(1,1): no occupancy pressure -> allocator free to grant up
// to the architectural 256 (8 waves of a 512-block at 2/SIMD).
// Phases B-D on wave 0 only (2 h-elements/lane, DPP reductions, fixed-5
// gather): 2 barriers/step. fp32 everywhere. History in LDS.
__global__
__attribute__((amdgpu_flat_work_group_size(512, 512), amdgpu_waves_per_eu(1, 1)))
void lstm_attn(
    const float* __restrict__ xw, const float* __restrict__ W_hh,
    const float* __restrict__ w_t, float* __restrict__ out)
{
  const int b   = blockIdx.x;
  const int tid = threadIdx.x;
  const int l   = tid & 63;       // lane
  const int wid = tid >> 6;
  const int g   = tid;

  __shared__ float ho[257 * 128];     // fp32 h history (131584 B)
  __shared__ float sh_part[512];      // finished gate preactivations
  __shared__ float sh_h[128];
  __shared__ float sh_d[257];         // cached tanh(h_t).w_b scores
  __shared__ int   sh_nnz;
  __shared__ int   sh_cidx[8];
  __shared__ float sh_cw[8];

  // one-time weight load: 32 named float4 = 128 VGPRs, pinned
  const float4* wr = (const float4*)(W_hh + (size_t)g * 128);
  float4 w0 = wr[0],   w1 = wr[1],   w2 = wr[2],   w3 = wr[3],
         w4 = wr[4],   w5 = wr[5],   w6 = wr[6],   w7 = wr[7],
         w8 = wr[8],   w9 = wr[9],   w10 = wr[10], w11 = wr[11],
         w12 = wr[12], w13 = wr[13], w14 = wr[14], w15 = wr[15],
         w16 = wr[16], w17 = wr[17], w18 = wr[18], w19 = wr[19],
         w20 = wr[20], w21 = wr[21], w22 = wr[22], w23 = wr[23],
         w24 = wr[24], w25 = wr[25], w26 = wr[26], w27 = wr[27],
         w28 = wr[28], w29 = wr[29], w30 = wr[30], w31 = wr[31];
  KEEP4(w0);  KEEP4(w1);  KEEP4(w2);  KEEP4(w3);
  KEEP4(w4);  KEEP4(w5);  KEEP4(w6);  KEEP4(w7);
  KEEP4(w8);  KEEP4(w9);  KEEP4(w10); KEEP4(w11);
  KEEP4(w12); KEEP4(w13); KEEP4(w14); KEEP4(w15);
  KEEP4(w16); KEEP4(w17); KEEP4(w18); KEEP4(w19);
  KEEP4(w20); KEEP4(w21); KEEP4(w22); KEEP4(w23);
  KEEP4(w24); KEEP4(w25); KEEP4(w26); KEEP4(w27);
  KEEP4(w28); KEEP4(w29); KEEP4(w30); KEEP4(w31);

  // wave0 per-lane persistent state (h elements j0=2l, j1=2l+1)
  const int j0 = 2 * l, j1 = 2 * l + 1;
  float c0 = 0.0f, c1 = 0.0f;
  float wa0 = 0.0f, wa1 = 0.0f, wb0 = 0.0f, wb1 = 0.0f;
  float t5_0 = 0.0f, t5_1 = NEGF, t5_2 = NEGF, t5_3 = NEGF, t5_4 = NEGF;
  if (wid == 0) {
    wa0 = w_t[j0];       wa1 = w_t[j1];
    wb0 = w_t[128 + j0]; wb1 = w_t[128 + j1];
    sh_h[j0] = 0.0f; sh_h[j1] = 0.0f;   // h(-1) = 0
    ho[j0]   = 0.0f; ho[j1]   = 0.0f;   // history row 0
  }
  if (tid == 0) { sh_d[0] = 0.0f; sh_nnz = 0; }
  __syncthreads();

  const float* xwb = xw + (size_t)b * 256 * 512;
  float xcur = xwb[g];                 // prefetched xw for step 0

  for (int i = 0; i < 256; ++i) {
    const int rem = i + 1;

    // ---- Phase A: gate preactivation (128 FMAs from pinned weights) ----
    float a0 = xcur, a1 = 0.0f, a2 = 0.0f, a3 = 0.0f;
    if (i < 255) xcur = xwb[(size_t)(i + 1) * 512 + g];   // prefetch
    const float4* hh4 = (const float4*)sh_h;
#define ASTEP(j) { float4 hv = hh4[j]; \
    a0 = fmaf(w##j.x, hv.x, a0); a1 = fmaf(w##j.y, hv.y, a1); \
    a2 = fmaf(w##j.z, hv.z, a2); a3 = fmaf(w##j.w, hv.w, a3); }
    ASTEP(0)  ASTEP(1)  ASTEP(2)  ASTEP(3)  ASTEP(4)  ASTEP(5)  ASTEP(6)  ASTEP(7)
    ASTEP(8)  ASTEP(9)  ASTEP(10) ASTEP(11) ASTEP(12) ASTEP(13) ASTEP(14) ASTEP(15)
    ASTEP(16) ASTEP(17) ASTEP(18) ASTEP(19) ASTEP(20) ASTEP(21) ASTEP(22) ASTEP(23)
    ASTEP(24) ASTEP(25) ASTEP(26) ASTEP(27) ASTEP(28) ASTEP(29) ASTEP(30) ASTEP(31)
#undef ASTEP
    sh_part[g] = (a0 + a1) + (a2 + a3);
    __syncthreads();                                      // S1

    if (wid == 0) {
      // ---- housekeeping + early loads (hide LDS latency) ----
      if (l < 8) { sh_cidx[l] = 0; sh_cw[l] = 0.0f; }     // pad gather slots
      if (l == 0) sh_nnz = 0;
      float d0 = sh_d[l], d1 = sh_d[l + 64],
            d2 = sh_d[l + 128], d3 = sh_d[l + 192];

      // ---- Phase B: LSTM cell (2 elements/lane) ----
      float2 Pi = ((const float2*)(sh_part      ))[l];
      float2 Pf = ((const float2*)(sh_part + 128))[l];
      float2 Pg = ((const float2*)(sh_part + 256))[l];
      float2 Po = ((const float2*)(sh_part + 384))[l];
      c0 = fsigmoid(Pf.x) * c0 + fsigmoid(Pi.x) * ftanh(Pg.x);
      c1 = fsigmoid(Pf.y) * c1 + fsigmoid(Pi.y) * ftanh(Pg.y);
      float hc0 = fsigmoid(Po.x) * ftanh(c0);
      float hc1 = fsigmoid(Po.y) * ftanh(c1);
      const float a = wave_allsum(ftanh(hc0) * wa0 + ftanh(hc1) * wa1);

      // ---- Phase C: scores at t = l, l+64, l+128, l+192 ----
      const float delta = (a + t5_4) + EPSF;
      float dv[4] = {d0, d1, d2, d3};
      float wv[4]; float wsum = 0.0f;
      #pragma unroll
      for (int m = 0; m < 4; ++m) {
        int t = l + 64 * m;
        float s = a + dv[m];
        float w = s - delta;
        w = (w > 0.0f) ? w : 0.0f;
        bool valid = (t < rem);
        wv[m] = valid ? w : 0.0f;
        wsum += wv[m];
        bool sel = valid && ((rem <= 5) || (w > 0.0f));
        if (sel) {
          int pp = atomicAdd(&sh_nnz, 1);
          float cv = (rem <= 5) ? s : w;
          if (pp < 8) { sh_cidx[pp] = t; sh_cw[pp] = cv; }
        }
      }
      wsum = wave_allsum(wsum);
      const float inv = (rem <= 5) ? 1.0f : 1.0f / (wsum + EPSF);
      if (i == 255) {
        #pragma unroll
        for (int m = 0; m < 4; ++m)
          out[4096 + b * 256 + (l + 64 * m)] = wv[m] * inv;  // final attn_w
      }

      // ---- Phase D: fixed-5 gather (nz<=5 provable; slots padded w=0) ----
      int   i0 = sh_cidx[0], i1 = sh_cidx[1], i2 = sh_cidx[2],
            i3 = sh_cidx[3], i4 = sh_cidx[4];
      float g0 = sh_cw[0], g1 = sh_cw[1], g2 = sh_cw[2],
            g3 = sh_cw[3], g4 = sh_cw[4];
      float at0 = g0 * ho[i0 * 128 + j0];
      float at1 = g0 * ho[i0 * 128 + j1];
      at0 = fmaf(g1, ho[i1 * 128 + j0], at0);
      at1 = fmaf(g1, ho[i1 * 128 + j1], at1);
      at0 = fmaf(g2, ho[i2 * 128 + j0], at0);
      at1 = fmaf(g2, ho[i2 * 128 + j1], at1);
      at0 = fmaf(g3, ho[i3 * 128 + j0], at0);
      at1 = fmaf(g3, ho[i3 * 128 + j1], at1);
      at0 = fmaf(g4, ho[i4 * 128 + j0], at0);
      at1 = fmaf(g4, ho[i4 * 128 + j1], at1);
      at0 *= inv; at1 *= inv;
      float hn0 = hc0 + at0, hn1 = hc1 + at1;
      sh_h[j0] = hn0; sh_h[j1] = hn1;
      ho[rem * 128 + j0] = hn0;
      ho[rem * 128 + j1] = hn1;
      if (i == 255) { out[b * 128 + j0] = at0; out[b * 128 + j1] = at1; }
      float dn = wave_allsum(ftanh(hn0) * wb0 + ftanh(hn1) * wb1);
      if (l == 0) sh_d[rem] = dn;
      // replicated top-5 insert (identical in every lane of wave 0)
      float v = dn;
      if (v > t5_0) { float t = t5_0; t5_0 = v; v = t; }
      if (v > t5_1) { float t = t5_1; t5_1 = v; v = t; }
      if (v > t5_2) { float t = t5_2; t5_2 = v; v = t; }
      if (v > t5_3) { float t = t5_3; t5_3 = v; v = t; }
      if (v > t5_4) { t5_4 = v; }
    }
    __syncthreads();                                      // S2
  }
}

extern "C" void kernel_launch(void* const* d_in, const int* in_sizes, int n_in,
                              void* d_out, int out_size, void* d_ws, size_t ws_size,
                              hipStream_t stream) {
  const float* x    = (const float*)d_in[0];  // (32,256,64)
  const float* W_ih = (const float*)d_in[1];  // (512,64)
  const float* W_hh = (const float*)d_in[2];  // (512,128)
  const float* b_ih = (const float*)d_in[3];  // (512,)
  const float* b_hh = (const float*)d_in[4];  // (512,)
  const float* w_t  = (const float*)d_in[5];  // (256,1)
  float* out = (float*)d_out;                 // [0:4096) attn_c, [4096:12288) attn_w

  float* xw = (float*)d_ws;                   // 32*256*512 fp32 = 16 MB

  xw_kernel<<<dim3(8, 32), 512, 0, stream>>>(x, W_ih, b_ih, b_hh, xw);
  lstm_attn<<<dim3(32), 512, 0, stream>>>(xw, W_hh, w_t, out);
}

// Round 10
// 607.836 us; speedup vs baseline: 1.2106x; 1.2106x over previous
//
#include <hip/hip_runtime.h>
#include <math.h>

#define NEGF -1000000000.0f
#define EPSF 1e-7f

// B=32, T=256, IN=64, H=128, 4H=512, TOP_K=5
//
// Register-grant law (9 rounds): arch-VGPR grant = 65536/block_threads
// (512thr -> 128, 1024thr -> 64), immune to launch_bounds/waves_per_eu.
// 128 fp32 weights/thread cannot live in arch VGPRs. Fix: 2 gates x K-half
// per thread; gate-A half (64 fp32) in pinned arch VGPRs, gate-B half
// (64 fp32) parked in AGPRs (unified file, outside the arch clamp):
// arch 128 + agpr 64 = 192/wave, x2 waves/SIMD = 384 <= 512 physical. OK.
// (r9's crash was an OOB LDS write in the rewritten xw_kernel, not AGPRs.)

#define KEEP4(v) __asm__ volatile("" : "+v"((v).x), "+v"((v).y), "+v"((v).z), "+v"((v).w))

__device__ __forceinline__ float fsigmoid(float x) {
  return 1.0f / (1.0f + __expf(-x));               // overflow -> correct limit
}
__device__ __forceinline__ float ftanh(float x) {
  return 1.0f - 2.0f / (1.0f + __expf(2.0f * x));  // limits +-1: correct
}

// wave64 all-reduce sum via DPP (row_shr 1/2/4/8 + row_bcast 15/31), ~35 cyc.
__device__ __forceinline__ float wave_allsum(float v) {
#if __has_builtin(__builtin_amdgcn_update_dpp) && __has_builtin(__builtin_amdgcn_readlane)
  float f = v;
#define DPPSTEP(ctrl, rmask) { \
    int t = __builtin_amdgcn_update_dpp(0, __builtin_bit_cast(int, f), \
                                        ctrl, rmask, 0xf, true); \
    f += __builtin_bit_cast(float, t); }
  DPPSTEP(0x111, 0xf)   // row_shr:1
  DPPSTEP(0x112, 0xf)   // row_shr:2
  DPPSTEP(0x114, 0xf)   // row_shr:4
  DPPSTEP(0x118, 0xf)   // row_shr:8  -> lane15 of each row has row sum
  DPPSTEP(0x142, 0xa)   // row_bcast:15 into rows 1,3
  DPPSTEP(0x143, 0x8)   // row_bcast:31 into row 3 -> lane 63 = total
#undef DPPSTEP
  return __builtin_bit_cast(float,
      __builtin_amdgcn_readlane(__builtin_bit_cast(int, f), 63));
#else
  for (int off = 1; off < 64; off <<= 1) v += __shfl_xor(v, off, 64);
  return v;
#endif
}

// Kernel 1: xw[b][t][g] = x[b][t] . W_ih[g] + (b_ih[g]+b_hh[g])
// grid (32, 32) = (T/8, B), 512 threads, thread = gate g, 8 timesteps.
// K-chunk outer loop streams one float4 of W_ih at a time into 8 live
// accumulators -> ~25 regs, spill-proof. (r9 bug fixed: loader guarded
// to 128 threads for the 8x64 tile.)
__global__ __launch_bounds__(512) void xw_kernel(
    const float* __restrict__ x, const float* __restrict__ W_ih,
    const float* __restrict__ b_ih, const float* __restrict__ b_hh,
    float* __restrict__ xw)
{
  const int t0 = blockIdx.x * 8;
  const int b  = blockIdx.y;
  const int g  = threadIdx.x;

  __shared__ float sx[8 * 64];               // 2 KB
  if (threadIdx.x < 128) {                   // 128 float4 = the whole tile
    int row = threadIdx.x >> 4, col = (threadIdx.x & 15) << 2;
    *(float4*)&sx[row * 64 + col] =
        *(const float4*)&x[(size_t)(b * 256 + t0 + row) * 64 + col];
  }
  const float bias = b_ih[g] + b_hh[g];
  __syncthreads();

  const float4* wp  = (const float4*)(W_ih + (size_t)g * 64);
  const float4* sx4 = (const float4*)sx;
  float acc[8];
  #pragma unroll
  for (int tt = 0; tt < 8; ++tt) acc[tt] = bias;
  #pragma unroll
  for (int c = 0; c < 16; ++c) {
    float4 w = wp[c];
    #pragma unroll
    for (int tt = 0; tt < 8; ++tt) {
      float4 xv = sx4[tt * 16 + c];          // wave-broadcast LDS read
      acc[tt] += w.x * xv.x + w.y * xv.y + w.z * xv.z + w.w * xv.w;
    }
  }
  #pragma unroll
  for (int tt = 0; tt < 8; ++tt)
    xw[(size_t)(b * 256 + t0 + tt) * 512 + g] = acc[tt];
}

// Kernel 2: full recurrence, one block per batch element, 512 threads.
// Thread t: K-half q = t>>8 (64 of 128 h values), gates gA = t&255 and
// gB = gA+256. gA's 64 fp32 weights: 16 pinned float4 arch VGPRs.
// gB's 64 fp32 weights: 64 AGPRs (v_accvgpr_write/read). Each h chunk
// read once from LDS feeds both gates -> 16 b128 reads/thread.
// Phases B-D on wave 0 (DPP reductions, fixed-5 gather): 2 barriers/step.
// fp32 everywhere. History in LDS.
__global__
__attribute__((amdgpu_flat_work_group_size(512, 512), amdgpu_waves_per_eu(2, 2)))
void lstm_attn(
    const float* __restrict__ xw, const float* __restrict__ W_hh,
    const float* __restrict__ w_t, float* __restrict__ out)
{
  const int b   = blockIdx.x;
  const int tid = threadIdx.x;
  const int l   = tid & 63;       // lane
  const int wid = tid >> 6;
  const int p   = tid & 255;
  const int q   = tid >> 8;       // K-half 0/1 (wave-uniform)
  const int gA  = p;
  const int gB  = p + 256;

  __shared__ float ho[257 * 128];     // fp32 h history (131584 B)
  __shared__ float sh_part[2 * 512];  // gate partials [q][gate] (4 KB)
  __shared__ float sh_h[128];
  __shared__ float sh_d[257];         // cached tanh(h_t).w_b scores
  __shared__ int   sh_nnz;
  __shared__ int   sh_cidx[8];
  __shared__ float sh_cw[8];

  // ---- gate-A half: 16 named float4 = 64 arch VGPRs, pinned ----
  const float4* pA = (const float4*)(W_hh + (size_t)gA * 128 + (q << 6));
  float4 wA0 = pA[0],   wA1 = pA[1],   wA2 = pA[2],   wA3 = pA[3],
         wA4 = pA[4],   wA5 = pA[5],   wA6 = pA[6],   wA7 = pA[7],
         wA8 = pA[8],   wA9 = pA[9],   wA10 = pA[10], wA11 = pA[11],
         wA12 = pA[12], wA13 = pA[13], wA14 = pA[14], wA15 = pA[15];
  KEEP4(wA0);  KEEP4(wA1);  KEEP4(wA2);  KEEP4(wA3);
  KEEP4(wA4);  KEEP4(wA5);  KEEP4(wA6);  KEEP4(wA7);
  KEEP4(wA8);  KEEP4(wA9);  KEEP4(wA10); KEEP4(wA11);
  KEEP4(wA12); KEEP4(wA13); KEEP4(wA14); KEEP4(wA15);

  // ---- gate-B half: 64 floats parked in AGPRs ----
  const float4* pB = (const float4*)(W_hh + (size_t)gB * 128 + (q << 6));
  float Ax0, Ay0, Az0, Aw0,   Ax1, Ay1, Az1, Aw1,
        Ax2, Ay2, Az2, Aw2,   Ax3, Ay3, Az3, Aw3,
        Ax4, Ay4, Az4, Aw4,   Ax5, Ay5, Az5, Aw5,
        Ax6, Ay6, Az6, Aw6,   Ax7, Ay7, Az7, Aw7,
        Ax8, Ay8, Az8, Aw8,   Ax9, Ay9, Az9, Aw9,
        Ax10, Ay10, Az10, Aw10, Ax11, Ay11, Az11, Aw11,
        Ax12, Ay12, Az12, Aw12, Ax13, Ay13, Az13, Aw13,
        Ax14, Ay14, Az14, Aw14, Ax15, Ay15, Az15, Aw15;
#define PARK4(j) { float4 tv = pB[j]; \
  __asm__ volatile("v_accvgpr_write_b32 %0, %1" : "=a"(Ax##j) : "v"(tv.x)); \
  __asm__ volatile("v_accvgpr_write_b32 %0, %1" : "=a"(Ay##j) : "v"(tv.y)); \
  __asm__ volatile("v_accvgpr_write_b32 %0, %1" : "=a"(Az##j) : "v"(tv.z)); \
  __asm__ volatile("v_accvgpr_write_b32 %0, %1" : "=a"(Aw##j) : "v"(tv.w)); }
  PARK4(0)  PARK4(1)  PARK4(2)  PARK4(3)
  PARK4(4)  PARK4(5)  PARK4(6)  PARK4(7)
  PARK4(8)  PARK4(9)  PARK4(10) PARK4(11)
  PARK4(12) PARK4(13) PARK4(14) PARK4(15)
#undef PARK4

  // wave0 per-lane persistent state (h elements j0=2l, j1=2l+1)
  const int j0 = 2 * l, j1 = 2 * l + 1;
  float c0 = 0.0f, c1 = 0.0f;
  float wa0 = 0.0f, wa1 = 0.0f, wb0 = 0.0f, wb1 = 0.0f;
  float t5_0 = 0.0f, t5_1 = NEGF, t5_2 = NEGF, t5_3 = NEGF, t5_4 = NEGF;
  if (wid == 0) {
    wa0 = w_t[j0];       wa1 = w_t[j1];
    wb0 = w_t[128 + j0]; wb1 = w_t[128 + j1];
    sh_h[j0] = 0.0f; sh_h[j1] = 0.0f;   // h(-1) = 0
    ho[j0]   = 0.0f; ho[j1]   = 0.0f;   // history row 0
  }
  if (tid == 0) { sh_d[0] = 0.0f; sh_nnz = 0; }
  __syncthreads();

  const float* xwb = xw + (size_t)b * 256 * 512;
  float xcurA = 0.0f, xcurB = 0.0f;
  if (q == 0) { xcurA = xwb[gA]; xcurB = xwb[gB]; }   // step-0 prefetch

  for (int i = 0; i < 256; ++i) {
    const int rem = i + 1;

    // ---- Phase A: gate partials; each h chunk feeds both gates ----
    float aA0 = xcurA, aA1 = 0.0f, aA2 = 0.0f, aA3 = 0.0f;
    float aB0 = xcurB, aB1 = 0.0f, aB2 = 0.0f, aB3 = 0.0f;
    if (q == 0 && i < 255) {          // prefetch next step's xw
      xcurA = xwb[(size_t)(i + 1) * 512 + gA];
      xcurB = xwb[(size_t)(i + 1) * 512 + gB];
    }
    const float4* hh4 = (const float4*)(sh_h + (q << 6));
#define ASTEP(j) { float4 hv = hh4[j]; float u0, u1, u2, u3; \
    __asm__ volatile("v_accvgpr_read_b32 %0, %1" : "=v"(u0) : "a"(Ax##j)); \
    __asm__ volatile("v_accvgpr_read_b32 %0, %1" : "=v"(u1) : "a"(Ay##j)); \
    __asm__ volatile("v_accvgpr_read_b32 %0, %1" : "=v"(u2) : "a"(Az##j)); \
    __asm__ volatile("v_accvgpr_read_b32 %0, %1" : "=v"(u3) : "a"(Aw##j)); \
    aA0 = fmaf(wA##j.x, hv.x, aA0); aA1 = fmaf(wA##j.y, hv.y, aA1); \
    aA2 = fmaf(wA##j.z, hv.z, aA2); aA3 = fmaf(wA##j.w, hv.w, aA3); \
    aB0 = fmaf(u0, hv.x, aB0); aB1 = fmaf(u1, hv.y, aB1); \
    aB2 = fmaf(u2, hv.z, aB2); aB3 = fmaf(u3, hv.w, aB3); }
    ASTEP(0)  ASTEP(1)  ASTEP(2)  ASTEP(3)
    ASTEP(4)  ASTEP(5)  ASTEP(6)  ASTEP(7)
    ASTEP(8)  ASTEP(9)  ASTEP(10) ASTEP(11)
    ASTEP(12) ASTEP(13) ASTEP(14) ASTEP(15)
#undef ASTEP
    sh_part[(q << 9) + gA] = (aA0 + aA1) + (aA2 + aA3);
    sh_part[(q << 9) + gB] = (aB0 + aB1) + (aB2 + aB3);
    __syncthreads();                                      // S1

    if (wid == 0) {
      // ---- housekeeping + early loads (hide LDS latency) ----
      if (l < 8) { sh_cidx[l] = 0; sh_cw[l] = 0.0f; }     // pad gather slots
      if (l == 0) sh_nnz = 0;
      float d0 = sh_d[l], d1 = sh_d[l + 64],
            d2 = sh_d[l + 128], d3 = sh_d[l + 192];

      // ---- Phase B: LSTM cell (2 elements/lane, combine K-halves) ----
#define GS(base) ({ \
      float2 x0 = ((const float2*)(sh_part       + (base)))[l]; \
      float2 x1 = ((const float2*)(sh_part + 512 + (base)))[l]; \
      float2 r; r.x = x0.x + x1.x; r.y = x0.y + x1.y; r; })
      float2 Pi = GS(0), Pf = GS(128), Pg = GS(256), Po = GS(384);
#undef GS
      c0 = fsigmoid(Pf.x) * c0 + fsigmoid(Pi.x) * ftanh(Pg.x);
      c1 = fsigmoid(Pf.y) * c1 + fsigmoid(Pi.y) * ftanh(Pg.y);
      float hc0 = fsigmoid(Po.x) * ftanh(c0);
      float hc1 = fsigmoid(Po.y) * ftanh(c1);
      const float a = wave_allsum(ftanh(hc0) * wa0 + ftanh(hc1) * wa1);

      // ---- Phase C: scores at t = l, l+64, l+128, l+192 ----
      const float delta = (a + t5_4) + EPSF;
      float dv[4] = {d0, d1, d2, d3};
      float wv[4]; float wsum = 0.0f;
      #pragma unroll
      for (int m = 0; m < 4; ++m) {
        int t = l + 64 * m;
        float s = a + dv[m];
        float w = s - delta;
        w = (w > 0.0f) ? w : 0.0f;
        bool valid = (t < rem);
        wv[m] = valid ? w : 0.0f;
        wsum += wv[m];
        bool sel = valid && ((rem <= 5) || (w > 0.0f));
        if (sel) {
          int pp = atomicAdd(&sh_nnz, 1);
          float cv = (rem <= 5) ? s : w;
          if (pp < 8) { sh_cidx[pp] = t; sh_cw[pp] = cv; }
        }
      }
      wsum = wave_allsum(wsum);
      const float inv = (rem <= 5) ? 1.0f : 1.0f / (wsum + EPSF);
      if (i == 255) {
        #pragma unroll
        for (int m = 0; m < 4; ++m)
          out[4096 + b * 256 + (l + 64 * m)] = wv[m] * inv;  // final attn_w
      }

      // ---- Phase D: fixed-5 gather (nz<=5 provable; slots padded w=0) ----
      int   i0 = sh_cidx[0], i1 = sh_cidx[1], i2 = sh_cidx[2],
            i3 = sh_cidx[3], i4 = sh_cidx[4];
      float g0 = sh_cw[0], g1 = sh_cw[1], g2 = sh_cw[2],
            g3 = sh_cw[3], g4 = sh_cw[4];
      float at0 = g0 * ho[i0 * 128 + j0];
      float at1 = g0 * ho[i0 * 128 + j1];
      at0 = fmaf(g1, ho[i1 * 128 + j0], at0);
      at1 = fmaf(g1, ho[i1 * 128 + j1], at1);
      at0 = fmaf(g2, ho[i2 * 128 + j0], at0);
      at1 = fmaf(g2, ho[i2 * 128 + j1], at1);
      at0 = fmaf(g3, ho[i3 * 128 + j0], at0);
      at1 = fmaf(g3, ho[i3 * 128 + j1], at1);
      at0 = fmaf(g4, ho[i4 * 128 + j0], at0);
      at1 = fmaf(g4, ho[i4 * 128 + j1], at1);
      at0 *= inv; at1 *= inv;
      float hn0 = hc0 + at0, hn1 = hc1 + at1;
      sh_h[j0] = hn0; sh_h[j1] = hn1;
      ho[rem * 128 + j0] = hn0;
      ho[rem * 128 + j1] = hn1;
      if (i == 255) { out[b * 128 + j0] = at0; out[b * 128 + j1] = at1; }
      float dn = wave_allsum(ftanh(hn0) * wb0 + ftanh(hn1) * wb1);
      if (l == 0) sh_d[rem] = dn;
      // replicated top-5 insert (identical in every lane of wave 0)
      float v = dn;
      if (v > t5_0) { float t = t5_0; t5_0 = v; v = t; }
      if (v > t5_1) { float t = t5_1; t5_1 = v; v = t; }
      if (v > t5_2) { float t = t5_2; t5_2 = v; v = t; }
      if (v > t5_3) { float t = t5_3; t5_3 = v; v = t; }
      if (v > t5_4) { t5_4 = v; }
    }
    __syncthreads();                                      // S2
  }
}

extern "C" void kernel_launch(void* const* d_in, const int* in_sizes, int n_in,
                              void* d_out, int out_size, void* d_ws, size_t ws_size,
                              hipStream_t stream) {
  const float* x    = (const float*)d_in[0];  // (32,256,64)
  const float* W_ih = (const float*)d_in[1];  // (512,64)
  const float* W_hh = (const float*)d_in[2];  // (512,128)
  const float* b_ih = (const float*)d_in[3];  // (512,)
  const float* b_hh = (const float*)d_in[4];  // (512,)
  const float* w_t  = (const float*)d_in[5];  // (256,1)
  float* out = (float*)d_out;                 // [0:4096) attn_c, [4096:12288) attn_w

  float* xw = (float*)d_ws;                   // 32*256*512 fp32 = 16 MB

  xw_kernel<<<dim3(32, 32), 512, 0, stream>>>(x, W_ih, b_ih, b_hh, xw);
  lstm_attn<<<dim3(32), 512, 0, stream>>>(xw, W_hh, w_t, out);
}